// Round 9
// baseline (200.500 us; speedup 1.0000x reference)
//
#include <hip/hip_runtime.h>

typedef __attribute__((ext_vector_type(8))) short short8;
typedef __attribute__((ext_vector_type(4))) short short4_t;
typedef __attribute__((ext_vector_type(2))) float float2_t;
typedef __attribute__((ext_vector_type(4))) float float4_t;
typedef __attribute__((ext_vector_type(4))) int int4_t;
typedef __attribute__((ext_vector_type(2))) unsigned uint2_t;

#define CH_STRIDE 4096        // 64*64 spatial per channel
#define IMG_STRIDE 524288     // 128 channels * 4096
#define HW 4096
#define VC72 72               // Vc row stride (shorts): 64 keys + 8 pad (16B-mult)
#define VT152 152             // Vtc row stride (shorts): 144 conv keys + 8 pad (16B-mult)

// float -> bf16 bits, round-to-nearest-even (finite inputs only)
static __device__ __forceinline__ short f2b(float x) {
    unsigned u = __builtin_bit_cast(unsigned, x);
    u = (u + 0x7fffu + ((u >> 16) & 1u)) >> 16;
    return (short)u;
}
static __device__ __forceinline__ float bitsf(unsigned u) { return __builtin_bit_cast(float, u); }
static __device__ __forceinline__ unsigned bitsu(float f) { return __builtin_bit_cast(unsigned, f); }

// Fused CSWin block: flash attention (S^T = K*Q^T, permlane P-exchange,
// O^T = V^T*P^T) + depthwise 3x3 conv rpe from LDS-resident V, one launch.
//
// R9: 4-wave workgroups. Ledger after 9 rounds: dur responds ONLY to resident
// waves (R0-3 vs R4-7) and to load/compute overlap (R8 broke it: +12us);
// occupancy never exceeded ~38% for any >=512-thread block (512-thr capped at
// 3 wg/CU, 1024-thr at ~1-2). Untested: small workgroups. This version splits
// each window-head into 4 q-quarter blocks of 256 threads (grid 2048 = 8/CU):
//   - per-block LDS 19.0KB = Kc(5.1, chunked) + Vc(4.6, current chunk) +
//     Vtc(9.5, conv region: 144 keys = this quarter's 16 h-rows + halo,
//     kb0 = qq*128-8, R6-proven guard-store trick) -> 8 x 19.4 <= 160KB.
//   - 8 independent 4-wave barrier domains per CU de-phase naturally (the
//     R8-safe de-convoy: staging stays in-loop/overlapped, barriers cheap).
//   - K/V staged 4x per window by qq-siblings; qq lives at bit 9 so siblings
//     are == mod 8 -> same XCD -> L2-served refetch (R4 precedent).
// Per-wave shape unchanged (qt=2, 32 q-rows/wave, permlane exchange, 2-deep
// register prefetch, 2 barriers/chunk). Loader: 256 thr = 32 d x 8 quad-
// slots, 2 float4/matrix/chunk/thread.
// Pre-committed reads: occ>=50 -> packing fixed, expect 58-68us; occ~22 ->
// cap is ~3 workgroups/CU regardless of size, occupancy axis closed.
__global__ __launch_bounds__(256) void cswin_fused(
    const float* __restrict__ temp, const float* __restrict__ cw,
    const float* __restrict__ cb, float* __restrict__ out)
{
    __shared__ short Kc[64 * 40];       // [key][d] pad-40, current chunk (5.1KB)
    __shared__ short Vc[32 * VC72];     // [d][key-local] current chunk (4.6KB)
    __shared__ short Vtc[32 * VT152];   // [d][key-kb0] conv region, persistent (9.5KB)

    int bx = blockIdx.x;                // (qq<<9)|(nw<<6)|(b<<2)|n
    int qq = bx >> 9;                   // q-quarter 0..3 (bit9+ -> same XCD as siblings)
    int nw = (bx >> 6) & 7;             // window column
    int b  = (bx >> 2) & 15;            // batch
    int n  = bx & 3;                    // head

    int t    = threadIdx.x;             // 0..255
    int wv   = t >> 6;                  // wave 0..3
    int lane = t & 63;
    int mr   = lane & 15;
    int q    = lane >> 4;

    int kb0 = qq * 128 - 8;             // conv V region = keys [kb0, kb0+144)

    const float* tq = temp + (size_t)b * 3 * IMG_STRIDE + (size_t)(n * 32) * CH_STRIDE + nw * 8;
    const float* tk = tq + IMG_STRIDE;
    const float* tv = tk + IMG_STRIDE;

    int row0 = qq * 128 + wv * 32;      // this wave's 32 q-rows
    const float qscale = 0.2550348889072310f;   // (1/sqrt(32)) * log2(e)

    // Q fragments (B-operand): lane holds Q[row0+qt*16+mr][q*8+j] * qscale
    short8 Qf[2];
    #pragma unroll
    for (int qt = 0; qt < 2; ++qt) {
        int l = row0 + qt * 16 + mr;
        int sp = (l >> 3) * 64 + (l & 7);
        short8 f;
        #pragma unroll
        for (int j = 0; j < 8; ++j)
            f[j] = f2b(tq[(q * 8 + j) * CH_STRIDE + sp] * qscale);
        Qf[qt] = f;
    }

    float4_t zero4 = {0.f, 0.f, 0.f, 0.f};
    float4_t acc[2][2];
    #pragma unroll
    for (int dt = 0; dt < 2; ++dt)
        #pragma unroll
        for (int qt = 0; qt < 2; ++qt)
            acc[dt][qt] = zero4;
    float lsum[2] = {0.f, 0.f};

    // loader mapping: 256 threads = 32 d x 8 quad-slots; thread (ld,qs)
    // handles key-quads qs, qs+8 per chunk -> 2 K + 2 V float4 loads.
    int ld = t >> 3;                    // channel d 0..31
    int qs = t & 7;                     // quad-slot 0..7
    const float* tkld = tk + (size_t)ld * CH_STRIDE;
    const float* tvld = tv + (size_t)ld * CH_STRIDE;
    // local keys kl0 = 4*(qs+8i); chunk-ch address = base + ch*512 + spb
    int kl0a = 4 * qs, kl0b = 4 * (qs + 8);
    int spba = (kl0a >> 3) * 64 + (kl0a & 7);
    int spbb = (kl0b >> 3) * 64 + (kl0b & 7);

    float4_t kq[2], vq[2];
    kq[0] = *reinterpret_cast<const float4_t*>(tkld + spba);
    kq[1] = *reinterpret_cast<const float4_t*>(tkld + spbb);
    vq[0] = *reinterpret_cast<const float4_t*>(tvld + spba);
    vq[1] = *reinterpret_cast<const float4_t*>(tvld + spbb);
    {   // prologue: stage chunk 0
        #pragma unroll
        for (int i = 0; i < 2; ++i) {
            int kl = i ? kl0b : kl0a;
            float4_t kk = kq[i], vv = vq[i];
            Kc[(kl + 0) * 40 + ld] = f2b(kk.x);
            Kc[(kl + 1) * 40 + ld] = f2b(kk.y);
            Kc[(kl + 2) * 40 + ld] = f2b(kk.z);
            Kc[(kl + 3) * 40 + ld] = f2b(kk.w);
            short4_t vs = { f2b(vv.x), f2b(vv.y), f2b(vv.z), f2b(vv.w) };
            *reinterpret_cast<short4_t*>(&Vc[ld * VC72 + kl]) = vs;
            int rk = kl - kb0;          // global key (ch 0) == kl
            if (rk >= 0 && rk < 144)
                *reinterpret_cast<short4_t*>(&Vtc[ld * VT152 + rk]) = vs;
        }
    }
    // issue chunk-1 loads (fly over compute 0)
    kq[0] = *reinterpret_cast<const float4_t*>(tkld + 512 + spba);
    kq[1] = *reinterpret_cast<const float4_t*>(tkld + 512 + spbb);
    vq[0] = *reinterpret_cast<const float4_t*>(tvld + 512 + spba);
    vq[1] = *reinterpret_cast<const float4_t*>(tvld + 512 + spbb);

    #pragma unroll 1
    for (int ch = 0; ch < 8; ++ch) {
        __syncthreads();       // publishes chunk ch's Kc/Vc/Vtc writes

        #pragma unroll
        for (int g = 0; g < 2; ++g) {
            // S^T tiles: D[m=key][n=qrow], keys g*32..g*32+31 (local to chunk)
            short8 KaA = *reinterpret_cast<const short8*>(&Kc[((2 * g) * 16 + mr) * 40 + q * 8]);
            short8 KaB = *reinterpret_cast<const short8*>(&Kc[((2 * g + 1) * 16 + mr) * 40 + q * 8]);
            unsigned pa0[2], pa1[2], pb0[2], pb1[2];
            #pragma unroll
            for (int qt = 0; qt < 2; ++qt) {
                float4_t sA = __builtin_amdgcn_mfma_f32_16x16x32_bf16(KaA, Qf[qt], zero4, 0, 0, 0);
                float4_t sB = __builtin_amdgcn_mfma_f32_16x16x32_bf16(KaB, Qf[qt], zero4, 0, 0, 0);
                float eA0 = __builtin_amdgcn_exp2f(sA.x), eA1 = __builtin_amdgcn_exp2f(sA.y);
                float eA2 = __builtin_amdgcn_exp2f(sA.z), eA3 = __builtin_amdgcn_exp2f(sA.w);
                float eB0 = __builtin_amdgcn_exp2f(sB.x), eB1 = __builtin_amdgcn_exp2f(sB.y);
                float eB2 = __builtin_amdgcn_exp2f(sB.z), eB3 = __builtin_amdgcn_exp2f(sB.w);
                lsum[qt] += ((eA0 + eA1) + (eA2 + eA3)) + ((eB0 + eB1) + (eB2 + eB3));
                // pack pairs (truncation) with one v_perm each: [lo16=e_even, hi16=e_odd]
                pa0[qt] = __builtin_amdgcn_perm(bitsu(eA1), bitsu(eA0), 0x07060302u);
                pa1[qt] = __builtin_amdgcn_perm(bitsu(eA3), bitsu(eA2), 0x07060302u);
                pb0[qt] = __builtin_amdgcn_perm(bitsu(eB1), bitsu(eB0), 0x07060302u);
                pb1[qt] = __builtin_amdgcn_perm(bitsu(eB3), bitsu(eB2), 0x07060302u);
            }
            // V^T A-fragments for this 32-key group (current chunk's Vc)
            int base = g * 32 + q * 8;
            short8 Va0 = *reinterpret_cast<const short8*>(&Vc[mr * VC72 + base]);
            short8 Va1 = *reinterpret_cast<const short8*>(&Vc[(16 + mr) * VC72 + base]);
            #pragma unroll
            for (int qt = 0; qt < 2; ++qt) {
                // C-layout P (keys q*4+r) -> B-operand (keys q*8+j) in-register:
                // word w of dest lane (q,mr) comes from lane (q&1)*32+(w>>1)*16+mr
                // of pa (q<2) / pb (q>=2). Two swap stages produce two words each.
                uint2_t re = __builtin_amdgcn_permlane32_swap(pa0[qt], pb0[qt], 0, 0);
                uint2_t we = __builtin_amdgcn_permlane16_swap(re.x, re.y, 0, 0);   // {w0, w2}
                uint2_t ro = __builtin_amdgcn_permlane32_swap(pa1[qt], pb1[qt], 0, 0);
                uint2_t wo = __builtin_amdgcn_permlane16_swap(ro.x, ro.y, 0, 0);   // {w1, w3}
                int4_t pi = { (int)we.x, (int)wo.x, (int)we.y, (int)wo.y };
                short8 Pb = __builtin_bit_cast(short8, pi);
                acc[0][qt] = __builtin_amdgcn_mfma_f32_16x16x32_bf16(Va0, Pb, acc[0][qt], 0, 0, 0);
                acc[1][qt] = __builtin_amdgcn_mfma_f32_16x16x32_bf16(Va1, Pb, acc[1][qt], 0, 0, 0);
            }
        }

        if (ch < 7) {
            __syncthreads();   // all waves done reading Kc/Vc for chunk ch
            // stage chunk ch+1 (loads issued one chunk ago, latency hidden)
            #pragma unroll
            for (int i = 0; i < 2; ++i) {
                int kl = i ? kl0b : kl0a;
                float4_t kk = kq[i], vv = vq[i];
                Kc[(kl + 0) * 40 + ld] = f2b(kk.x);
                Kc[(kl + 1) * 40 + ld] = f2b(kk.y);
                Kc[(kl + 2) * 40 + ld] = f2b(kk.z);
                Kc[(kl + 3) * 40 + ld] = f2b(kk.w);
                short4_t vs = { f2b(vv.x), f2b(vv.y), f2b(vv.z), f2b(vv.w) };
                *reinterpret_cast<short4_t*>(&Vc[ld * VC72 + kl]) = vs;
                int rk = (ch + 1) * 64 + kl - kb0;
                if (rk >= 0 && rk < 144)
                    *reinterpret_cast<short4_t*>(&Vtc[ld * VT152 + rk]) = vs;
            }
            if (ch < 6) {      // issue chunk ch+2 loads (fly over compute ch+1)
                int off = (ch + 2) * 512;
                kq[0] = *reinterpret_cast<const float4_t*>(tkld + off + spba);
                kq[1] = *reinterpret_cast<const float4_t*>(tkld + off + spbb);
                vq[0] = *reinterpret_cast<const float4_t*>(tvld + off + spba);
                vq[1] = *reinterpret_cast<const float4_t*>(tvld + off + spbb);
            }
        }
    }

    // softmax denominators: reduce across quads, invert
    float inv[2];
    #pragma unroll
    for (int qt = 0; qt < 2; ++qt) {
        float v = lsum[qt];
        v += __shfl_xor(v, 16);
        v += __shfl_xor(v, 32);
        inv[qt] = 1.0f / v;
    }

    // O store: lane holds O[qrow=row0+qt*16+mr][c = n*32 + dt*16 + q*4 + r]
    float* outb = out + (size_t)b * HW * 128 + nw * 8 * 128 + n * 32;
    #pragma unroll
    for (int qt = 0; qt < 2; ++qt) {
        int l = row0 + qt * 16 + mr;
        size_t basep = (size_t)((l >> 3) * 64 + (l & 7)) * 128;
        #pragma unroll
        for (int dt = 0; dt < 2; ++dt) {
            float4_t o = acc[dt][qt] * inv[qt];
            *reinterpret_cast<float4_t*>(outb + basep + dt * 16 + q * 4) = o;
        }
    }

    __syncthreads();   // O-stores visible block-wide; Vtc complete

    // ---- depthwise 3x3 conv + bias (window-local SAME pad) from LDS V, RMW out
    // This block covers its own quarter rows: h = qq*16 + 0..15 (== this
    // block's O rows -> RMW block-local; heads/quarters/windows disjoint).
    // Vtc holds keys [kb0, kb0+144) == exactly hh in [qq*16-1, qq*16+16].
    // 256 threads = 16 h-rows x 16 channel-pairs.
    int c2 = (t & 15) * 2;             // relative channel 0,2,..,30
    int h  = qq * 16 + (t >> 4);       // window-global row
    float2_t outv[8];
    #pragma unroll
    for (int cc = 0; cc < 2; ++cc) {
        int c = c2 + cc;
        float w9[9];
        #pragma unroll
        for (int i = 0; i < 9; ++i) w9[i] = cw[(n * 32 + c) * 9 + i];
        float bias = cb[n * 32 + c];
        float rv[3][8];
        #pragma unroll
        for (int rr = 0; rr < 3; ++rr) {
            int hh = h - 1 + rr;
            if (hh >= 0 && hh < 64) {
                short8 u = *reinterpret_cast<const short8*>(&Vtc[c * VT152 + (hh * 8 - kb0)]);
                #pragma unroll
                for (int j = 0; j < 8; ++j)
                    rv[rr][j] = bitsf(((unsigned)(unsigned short)u[j]) << 16);
            } else {
                #pragma unroll
                for (int j = 0; j < 8; ++j) rv[rr][j] = 0.f;
            }
        }
        #pragma unroll
        for (int w = 0; w < 8; ++w) {
            float o = bias;
            #pragma unroll
            for (int rr = 0; rr < 3; ++rr) {
                if (w > 0) o += rv[rr][w - 1] * w9[rr * 3 + 0];
                o += rv[rr][w] * w9[rr * 3 + 1];
                if (w < 7) o += rv[rr][w + 1] * w9[rr * 3 + 2];
            }
            outv[w][cc] = o;
        }
    }
    #pragma unroll
    for (int w = 0; w < 8; ++w) {
        size_t off = (size_t)h * 8192 + w * 128 + c2;
        float2_t cur = *reinterpret_cast<const float2_t*>(outb + off);
        cur += outv[w];
        *reinterpret_cast<float2_t*>(outb + off) = cur;
    }
}

extern "C" void kernel_launch(void* const* d_in, const int* in_sizes, int n_in,
                              void* d_out, int out_size, void* d_ws, size_t ws_size,
                              hipStream_t stream) {
    const float* temp = (const float*)d_in[0];
    const float* cw   = (const float*)d_in[1];
    const float* cb   = (const float*)d_in[2];
    float* out = (float*)d_out;
    hipLaunchKernelGGL(cswin_fused, dim3(2048), dim3(256), 0, stream, temp, cw, cb, out);
}

// Round 10
// 186.499 us; speedup vs baseline: 1.0751x; 1.0751x over previous
//
#include <hip/hip_runtime.h>

typedef __attribute__((ext_vector_type(8))) short short8;
typedef __attribute__((ext_vector_type(2))) float float2_t;
typedef __attribute__((ext_vector_type(4))) float float4_t;
typedef __attribute__((ext_vector_type(4))) int int4_t;
typedef __attribute__((ext_vector_type(2))) unsigned uint2_t;
typedef __attribute__((ext_vector_type(4))) unsigned uint4_t;

#define CH_STRIDE 4096        // 64*64 spatial per channel
#define IMG_STRIDE 524288     // 128 channels * 4096
#define HW 4096
#define V520 520              // Vt row stride (shorts); 1040B rows keep 16B align

static __device__ __forceinline__ float bitsf(unsigned u) { return __builtin_bit_cast(float, u); }
static __device__ __forceinline__ unsigned bitsu(float f) { return __builtin_bit_cast(unsigned, f); }

// f32 pair -> packed 2x bf16 (RNE), one VALU op. No builtin on gfx950 (m240);
// hand f2b bit-math costs ~4 VALU each and the compiler can't fold it.
static __device__ __forceinline__ unsigned cvt_pk(float lo, float hi) {
    unsigned r;
    asm("v_cvt_pk_bf16_f32 %0, %1, %2" : "=v"(r) : "v"(lo), "v"(hi));
    return r;
}

// Fused CSWin block: flash attention (S^T = K*Q^T, permlane P-exchange,
// O^T = V^T*P^T) + depthwise 3x3 conv rpe from LDS-resident V, one launch.
//
// R10 = R7 base (best per-dispatch 76.1us: grid 512 x 1024thr, 16 waves/blk,
// qt=2, full-window Vt, chunked Kc, 2-deep reg prefetch, permlane exchange)
// + v_cvt_pk_bf16_f32 conversion diet.
// Ledger: occupancy axis CLOSED (R5/R6/R9: 512-thr caps at 3 wg/CU, 256-thr
// at ~2.2, 1024-thr ~1.5; duplication for more blocks is HBM-priced, R9).
// Memory exonerated (R7 L3-resident replays: same 76us at FETCH~0). Barriers
// exonerated (R2). Exchange exonerated (R3). R8: prologue mega-staging
// serializes load latency (+12us) — staging must stay distributed in-loop.
// VALUBusy ~30% = busiest pipe; ~3.4K VALU instr/wave, ~3x the algorithmic
// minimum -> attack the issued stream: all f32->bf16 via cvt_pk (1 op for 2
// floats, RNE = same rounding as before): Q 8 f2b->4 cvt_pk; K staging
// 4 f2b->2 cvt_pk+2 shifts; V staging 4 f2b->2 cvt_pk packed store.
// ~500-600 VALU ops/thread saved (~15-20% of stream).
__global__ __launch_bounds__(1024) void cswin_fused(
    const float* __restrict__ temp, const float* __restrict__ cw,
    const float* __restrict__ cb, float* __restrict__ out)
{
    __shared__ short Kc[64 * 40];      // [key][d] pad-40, current chunk
    __shared__ short Vt[32 * V520];    // [d][l] full 512-key window, persistent

    int bx = blockIdx.x;
    int nw = bx >> 6;          // window column 0..7 (high bits: XCD L2 locality)
    int r  = bx & 63;
    int b  = r >> 2;           // batch 0..15
    int n  = r & 3;            // head 0..3

    int t    = threadIdx.x;
    int wv   = t >> 6;         // wave 0..15
    int lane = t & 63;
    int mr   = lane & 15;
    int q    = lane >> 4;

    const float* tq = temp + (size_t)b * 3 * IMG_STRIDE + (size_t)(n * 32) * CH_STRIDE + nw * 8;
    const float* tk = tq + IMG_STRIDE;
    const float* tv = tk + IMG_STRIDE;

    int row0 = wv * 32;        // this wave's 32 q-rows (16 waves x 32 = 512)
    const float qscale = 0.2550348889072310f;   // (1/sqrt(32)) * log2(e)

    // Q fragments (B-operand): lane holds Q[row0+qt*16+mr][q*8+j] * qscale
    short8 Qf[2];
    #pragma unroll
    for (int qt = 0; qt < 2; ++qt) {
        int l = row0 + qt * 16 + mr;
        int sp = (l >> 3) * 64 + (l & 7);
        float f[8];
        #pragma unroll
        for (int j = 0; j < 8; ++j)
            f[j] = tq[(q * 8 + j) * CH_STRIDE + sp] * qscale;
        uint4_t up = { cvt_pk(f[0], f[1]), cvt_pk(f[2], f[3]),
                       cvt_pk(f[4], f[5]), cvt_pk(f[6], f[7]) };
        Qf[qt] = __builtin_bit_cast(short8, up);
    }

    float4_t zero4 = {0.f, 0.f, 0.f, 0.f};
    float4_t acc[2][2];
    #pragma unroll
    for (int dt = 0; dt < 2; ++dt)
        #pragma unroll
        for (int qt = 0; qt < 2; ++qt)
            acc[dt][qt] = zero4;
    float lsum[2] = {0.f, 0.f};

    // loader mapping: 1024 threads = 32 d x 32 key-slots; thread (ld,seg)
    // handles keys seg+32i (i=0,1) -> 2 K + 2 V loads/chunk/thread.
    int ld  = t >> 5;          // channel d 0..31
    int seg = t & 31;
    const float* tkld = tk + (size_t)ld * CH_STRIDE;
    const float* tvld = tv + (size_t)ld * CH_STRIDE;

    float kx[2], vx[2];
    #pragma unroll
    for (int i = 0; i < 2; ++i) {      // load chunk 0
        int lb = seg + 32 * i;
        int sp = (lb >> 3) * 64 + (lb & 7);
        kx[i] = tkld[sp]; vx[i] = tvld[sp];
    }
    {   // prologue: stage chunk 0 into Kc / Vt[0..63]
        unsigned pk = cvt_pk(kx[0], kx[1]);     // lo = key seg, hi = key seg+32
        Kc[(seg)      * 40 + ld] = (short)(pk & 0xffffu);
        Kc[(seg + 32) * 40 + ld] = (short)(pk >> 16);
        unsigned pv = cvt_pk(vx[0], vx[1]);
        Vt[ld * V520 + seg]      = (short)(pv & 0xffffu);
        Vt[ld * V520 + seg + 32] = (short)(pv >> 16);
    }
    #pragma unroll
    for (int i = 0; i < 2; ++i) {      // issue chunk-1 loads (fly over compute 0)
        int lb = 64 + seg + 32 * i;
        int sp = (lb >> 3) * 64 + (lb & 7);
        kx[i] = tkld[sp]; vx[i] = tvld[sp];
    }

    #pragma unroll 1
    for (int ch = 0; ch < 8; ++ch) {
        __syncthreads();       // publishes chunk ch's Kc/Vt writes

        #pragma unroll
        for (int g = 0; g < 2; ++g) {
            // S^T tiles: D[m=key][n=qrow], keys g*32..g*32+31 (local to chunk)
            short8 KaA = *reinterpret_cast<const short8*>(&Kc[((2 * g) * 16 + mr) * 40 + q * 8]);
            short8 KaB = *reinterpret_cast<const short8*>(&Kc[((2 * g + 1) * 16 + mr) * 40 + q * 8]);
            unsigned pa0[2], pa1[2], pb0[2], pb1[2];
            #pragma unroll
            for (int qt = 0; qt < 2; ++qt) {
                float4_t sA = __builtin_amdgcn_mfma_f32_16x16x32_bf16(KaA, Qf[qt], zero4, 0, 0, 0);
                float4_t sB = __builtin_amdgcn_mfma_f32_16x16x32_bf16(KaB, Qf[qt], zero4, 0, 0, 0);
                float eA0 = __builtin_amdgcn_exp2f(sA.x), eA1 = __builtin_amdgcn_exp2f(sA.y);
                float eA2 = __builtin_amdgcn_exp2f(sA.z), eA3 = __builtin_amdgcn_exp2f(sA.w);
                float eB0 = __builtin_amdgcn_exp2f(sB.x), eB1 = __builtin_amdgcn_exp2f(sB.y);
                float eB2 = __builtin_amdgcn_exp2f(sB.z), eB3 = __builtin_amdgcn_exp2f(sB.w);
                lsum[qt] += ((eA0 + eA1) + (eA2 + eA3)) + ((eB0 + eB1) + (eB2 + eB3));
                // pack pairs with one v_perm each (truncation): [lo16=e_even, hi16=e_odd]
                pa0[qt] = __builtin_amdgcn_perm(bitsu(eA1), bitsu(eA0), 0x07060302u);
                pa1[qt] = __builtin_amdgcn_perm(bitsu(eA3), bitsu(eA2), 0x07060302u);
                pb0[qt] = __builtin_amdgcn_perm(bitsu(eB1), bitsu(eB0), 0x07060302u);
                pb1[qt] = __builtin_amdgcn_perm(bitsu(eB3), bitsu(eB2), 0x07060302u);
            }
            // V^T A-fragments for this 32-key group
            int base = ch * 64 + g * 32 + q * 8;
            short8 Va0 = *reinterpret_cast<const short8*>(&Vt[mr * V520 + base]);
            short8 Va1 = *reinterpret_cast<const short8*>(&Vt[(16 + mr) * V520 + base]);
            #pragma unroll
            for (int qt = 0; qt < 2; ++qt) {
                // C-layout P (keys q*4+r) -> B-operand (keys q*8+j) in-register:
                // word w of dest lane (q,mr) comes from lane (q&1)*32+(w>>1)*16+mr
                // of pa (q<2) / pb (q>=2). Two swap stages produce two words each.
                uint2_t re = __builtin_amdgcn_permlane32_swap(pa0[qt], pb0[qt], 0, 0);
                uint2_t we = __builtin_amdgcn_permlane16_swap(re.x, re.y, 0, 0);   // {w0, w2}
                uint2_t ro = __builtin_amdgcn_permlane32_swap(pa1[qt], pb1[qt], 0, 0);
                uint2_t wo = __builtin_amdgcn_permlane16_swap(ro.x, ro.y, 0, 0);   // {w1, w3}
                int4_t pi = { (int)we.x, (int)wo.x, (int)we.y, (int)wo.y };
                short8 Pb = __builtin_bit_cast(short8, pi);
                acc[0][qt] = __builtin_amdgcn_mfma_f32_16x16x32_bf16(Va0, Pb, acc[0][qt], 0, 0, 0);
                acc[1][qt] = __builtin_amdgcn_mfma_f32_16x16x32_bf16(Va1, Pb, acc[1][qt], 0, 0, 0);
            }
        }

        if (ch < 7) {
            __syncthreads();   // all waves done reading Kc for chunk ch
            // stage chunk ch+1 (loads issued one chunk ago, latency hidden)
            {
                unsigned pk = cvt_pk(kx[0], kx[1]);
                Kc[(seg)      * 40 + ld] = (short)(pk & 0xffffu);
                Kc[(seg + 32) * 40 + ld] = (short)(pk >> 16);
                unsigned pv = cvt_pk(vx[0], vx[1]);
                Vt[ld * V520 + (ch + 1) * 64 + seg]      = (short)(pv & 0xffffu);
                Vt[ld * V520 + (ch + 1) * 64 + seg + 32] = (short)(pv >> 16);
            }
            if (ch < 6) {      // issue chunk ch+2 loads (fly over compute ch+1)
                #pragma unroll
                for (int i = 0; i < 2; ++i) {
                    int lb = (ch + 2) * 64 + seg + 32 * i;
                    int sp = (lb >> 3) * 64 + (lb & 7);
                    kx[i] = tkld[sp]; vx[i] = tvld[sp];
                }
            }
        }
    }

    // softmax denominators: reduce across quads, invert
    float inv[2];
    #pragma unroll
    for (int qt = 0; qt < 2; ++qt) {
        float v = lsum[qt];
        v += __shfl_xor(v, 16);
        v += __shfl_xor(v, 32);
        inv[qt] = 1.0f / v;
    }

    // O store: lane holds O[qrow=row0+qt*16+mr][c = n*32 + dt*16 + q*4 + r]
    float* outb = out + (size_t)b * HW * 128 + nw * 8 * 128 + n * 32;
    #pragma unroll
    for (int qt = 0; qt < 2; ++qt) {
        int l = row0 + qt * 16 + mr;
        size_t basep = (size_t)((l >> 3) * 64 + (l & 7)) * 128;
        #pragma unroll
        for (int dt = 0; dt < 2; ++dt) {
            float4_t o = acc[dt][qt] * inv[qt];
            *reinterpret_cast<float4_t*>(outb + basep + dt * 16 + q * 4) = o;
        }
    }

    __syncthreads();   // O-stores visible block-wide; Vt complete since last barrier

    // ---- depthwise 3x3 conv + bias (window-local SAME pad) from LDS V, RMW out
    // 1024 threads = 64 h-rows x 16 channel-pairs; each thread 2 channels.
    int c2 = (t & 15) * 2;             // relative channel 0,2,..,30
    int h  = t >> 4;                   // 0..63
    float2_t outv[8];
    #pragma unroll
    for (int cc = 0; cc < 2; ++cc) {
        int c = c2 + cc;
        float w9[9];
        #pragma unroll
        for (int i = 0; i < 9; ++i) w9[i] = cw[(n * 32 + c) * 9 + i];
        float bias = cb[n * 32 + c];
        float rv[3][8];
        #pragma unroll
        for (int rr = 0; rr < 3; ++rr) {
            int hh = h - 1 + rr;
            if (hh >= 0 && hh < 64) {
                short8 u = *reinterpret_cast<const short8*>(&Vt[c * V520 + hh * 8]);
                #pragma unroll
                for (int j = 0; j < 8; ++j)
                    rv[rr][j] = bitsf(((unsigned)(unsigned short)u[j]) << 16);
            } else {
                #pragma unroll
                for (int j = 0; j < 8; ++j) rv[rr][j] = 0.f;
            }
        }
        #pragma unroll
        for (int w = 0; w < 8; ++w) {
            float o = bias;
            #pragma unroll
            for (int rr = 0; rr < 3; ++rr) {
                if (w > 0) o += rv[rr][w - 1] * w9[rr * 3 + 0];
                o += rv[rr][w] * w9[rr * 3 + 1];
                if (w < 7) o += rv[rr][w + 1] * w9[rr * 3 + 2];
            }
            outv[w][cc] = o;
        }
    }
    #pragma unroll
    for (int w = 0; w < 8; ++w) {
        size_t off = (size_t)h * 8192 + w * 128 + c2;
        float2_t cur = *reinterpret_cast<const float2_t*>(outb + off);
        cur += outv[w];
        *reinterpret_cast<float2_t*>(outb + off) = cur;
    }
}

extern "C" void kernel_launch(void* const* d_in, const int* in_sizes, int n_in,
                              void* d_out, int out_size, void* d_ws, size_t ws_size,
                              hipStream_t stream) {
    const float* temp = (const float*)d_in[0];
    const float* cw   = (const float*)d_in[1];
    const float* cb   = (const float*)d_in[2];
    float* out = (float*)d_out;
    hipLaunchKernelGGL(cswin_fused, dim3(512), dim3(1024), 0, stream, temp, cw, cb, out);
}